// Round 1
// baseline (640.268 us; speedup 1.0000x reference)
//
#include <hip/hip_runtime.h>
#include <stdint.h>

// Viterbi CRF decode: B=1024, T=1024, N=34 (32 tags + START=32 + END=33)
#define BB 1024
#define TT 1024
#define NN 34
#define NP 36          // padded state dim (2 pad states, score -1e30)
#define CH 9           // k-chunk per thread (4 chunks x 9 = 36)
#define NB 4           // batches per block
#define TPB (NB * NN * 4)   // 544 threads
#define NEGV -6969.0f
#define PADV -1.0e30f

template<int C>
__device__ __forceinline__ int dpp_i(int x) {
    return __builtin_amdgcn_update_dpp(0, x, C, 0xF, 0xF, true);
}
template<int C>
__device__ __forceinline__ float dpp_f(float x) {
    return __int_as_float(dpp_i<C>(__float_as_int(x)));
}

__global__ __launch_bounds__(TPB) void viterbi_fwd(
        const float* __restrict__ feat,   // [B,T,34]
        const float* __restrict__ trans,  // [34,34]
        unsigned char* __restrict__ bp,   // [B,T,34]
        float* __restrict__ sfin)         // [B,34]
{
    __shared__ float s_lds[2][NB * NP];

    const int tid = threadIdx.x;
    const int bl  = tid / 136;        // 0..3 local batch
    const int r   = tid % 136;
    const int j   = r >> 2;           // 0..33 target state
    const int h   = r & 3;            // 0..3 k-quarter (quad lanes!)
    const int bg  = blockIdx.x * NB + bl;
    const int k0  = h * CH;           // 0,9,18,27

    // transition chunk in registers (constant over t)
    float tr[CH];
#pragma unroll
    for (int i = 0; i < CH; ++i) {
        int k = k0 + i;
        tr[i] = (k < NN) ? trans[j * NN + k] : 0.0f;
    }

    // init both LDS score buffers (pads = -1e30, init scores in buf0)
    for (int e = tid; e < 2 * NB * NP; e += TPB) {
        int kk = e % NP;
        float v = (kk >= NN) ? PADV : ((kk == 32) ? 0.0f : NEGV);
        s_lds[0][0] = s_lds[0][0]; // no-op keep compiler quiet
        ((float*)s_lds)[e] = v;
    }

    const float* fptr = feat + (size_t)bg * TT * NN + j;
    float f = fptr[0];

    unsigned char* bprow = bp + (size_t)bg * TT * NN + j;

    __syncthreads();

    int cur = 0;
    for (int t = 0; t < TT; ++t) {
        // read score chunk for this k-quarter
        const float* sb = &s_lds[cur][bl * NP + k0];
        float sv[CH];
#pragma unroll
        for (int i = 0; i < CH; ++i) sv[i] = sb[i];

        // prefetch next feature (clamped at the end)
        float fn = fptr[(size_t)((t + 1 < TT) ? t + 1 : t) * NN];

        // partial max/argmax over this k-chunk, reference fp order (s+f)+t,
        // strict > with ascending k => first-index tie-break
        float m = -3.0e38f;
        int am = k0;
#pragma unroll
        for (int i = 0; i < CH; ++i) {
            float v = (sv[i] + f) + tr[i];
            bool gt = v > m;
            am = gt ? (k0 + i) : am;
            m  = gt ? v : m;
        }

        // combine the 4 k-quarters inside the DPP quad (lex max on (v,-k))
        {
            float vo = dpp_f<0xB1>(m);  // quad_perm(1,0,3,2): xor 1
            int   ko = dpp_i<0xB1>(am);
            bool take = (vo > m) || (vo == m && ko < am);
            m  = take ? vo : m;
            am = take ? ko : am;
            vo = dpp_f<0x4E>(m);        // quad_perm(2,3,0,1): xor 2
            ko = dpp_i<0x4E>(am);
            take = (vo > m) || (vo == m && ko < am);
            m  = take ? vo : m;
            am = take ? ko : am;
        }

        int nxt = cur ^ 1;
        if (h == 0) {
            s_lds[nxt][bl * NP + j] = m;
            bprow[(size_t)t * NN] = (unsigned char)am;
        }
        f = fn;
        cur = nxt;
        __syncthreads();
    }

    if (h == 0) sfin[bg * NN + j] = s_lds[cur][bl * NP + j];
}

// chunked-hypothesis backtrack: 16 chunks x 64 steps, 34 hypotheses each
__global__ __launch_bounds__(TPB) void viterbi_btk(
        const unsigned char* __restrict__ bp,   // [B,T,34]
        const float* __restrict__ sfin,         // [B,34]
        const float* __restrict__ trans,        // [34,34]
        float* __restrict__ out)                // best[B] ++ path[B,T+1]
{
    __shared__ unsigned char bps[TT * NN];      // 34816 B
    __shared__ float fsb[NN];
    __shared__ int   Fm[16][NN];
    __shared__ int   Eb[16];
    __shared__ int   idx_s;

    const int b = blockIdx.x;
    const int tid = threadIdx.x;

    // stage this batch's backpointers into LDS (16B vectors, 34816%16==0)
    {
        const uint4* src = (const uint4*)(bp + (size_t)b * (TT * NN));
        uint4* dst = (uint4*)bps;
        for (int i = tid; i < (TT * NN) / 16; i += TPB) dst[i] = src[i];
    }
    if (tid < NN) fsb[tid] = sfin[b * NN + tid] + trans[33 * NN + tid];
    __syncthreads();

    if (tid == 0) {
        float bm = fsb[0]; int bi = 0;
        for (int k = 1; k < NN; ++k) {
            if (fsb[k] > bm) { bm = fsb[k]; bi = k; }
        }
        out[b] = bm;
        idx_s = bi;
    }
    __syncthreads();

    const int c = tid / NN;   // chunk 0..15
    const int x = tid % NN;   // hypothesis state at chunk end

    // pass 1: chunk map F_c[x] = state at time c*64 given state x at (c+1)*64
    {
        int m = x;
        for (int i = 63; i >= 0; --i) m = bps[(c * 64 + i) * NN + m];
        Fm[c][x] = m;
    }
    __syncthreads();

    if (tid == 0) {
        int e = idx_s;
        Eb[15] = e;
        for (int cc = 15; cc >= 1; --cc) { e = Fm[cc][e]; Eb[cc - 1] = e; }
    }
    __syncthreads();

    // pass 2: winning hypothesis per chunk emits the path
    float* po = out + BB + (size_t)b * (TT + 1);
    if (x == Eb[c]) {
        int m = x;
        for (int i = 63; i >= 0; --i) {
            m = bps[(c * 64 + i) * NN + m];
            po[c * 64 + i] = (float)m;
        }
    }
    if (tid == 0) po[TT] = (float)idx_s;
}

extern "C" void kernel_launch(void* const* d_in, const int* in_sizes, int n_in,
                              void* d_out, int out_size, void* d_ws, size_t ws_size,
                              hipStream_t stream) {
    const float* feat  = (const float*)d_in[0];   // [1024,1024,34]
    const float* trans = (const float*)d_in[1];   // [34,34]
    float* out = (float*)d_out;                   // 1024 + 1024*1025 floats

    unsigned char* bp = (unsigned char*)d_ws;                       // 35,651,584 B
    float* sfin = (float*)((char*)d_ws + (size_t)BB * TT * NN);     // 139,264 B

    viterbi_fwd<<<BB / NB, TPB, 0, stream>>>(feat, trans, bp, sfin);
    viterbi_btk<<<BB, TPB, 0, stream>>>(bp, sfin, trans, out);
}

// Round 2
// 547.453 us; speedup vs baseline: 1.1695x; 1.1695x over previous
//
#include <hip/hip_runtime.h>
#include <stdint.h>

// Viterbi CRF decode: B=1024, T=1024, N=34 (32 tags + START=32 + END=33)
#define BB 1024
#define TT 1024
#define NN 34
#define NP 36            // padded state dim in LDS score buffers
#define NB 2             // batches per block
#define TPB (NB * 136)   // 272 threads = 2 batches x (34 j x 4 h)
#define NEGV -6969.0f
#define PADV -1.0e30f

template<int C>
__device__ __forceinline__ int dpp_i(int x) {
    return __builtin_amdgcn_update_dpp(0, x, C, 0xF, 0xF, true);
}
template<int C>
__device__ __forceinline__ float dpp_f(float x) {
    return __int_as_float(dpp_i<C>(__float_as_int(x)));
}

// Barrier that drains LDS (lgkmcnt) only: global prefetch loads stay in
// flight across steps (plain __syncthreads would force vmcnt(0) -> exposes
// full HBM latency on the critical path every step).
__device__ __forceinline__ void lds_barrier() {
    asm volatile("s_waitcnt lgkmcnt(0)\n\ts_barrier" ::: "memory");
}

__global__ __launch_bounds__(TPB, 3) void viterbi_full(
        const float* __restrict__ feat,   // [B,T,34]
        const float* __restrict__ trans,  // [34,34]
        unsigned char* __restrict__ bpg,  // workspace [B,T,34] backpointers
        float* __restrict__ out)          // best[B] ++ path[B,T+1]
{
    __shared__ float sbuf[2][NB][NP];     // ping-pong score buffers
    __shared__ float fsb[NB][NN];
    __shared__ unsigned char Fm[NB][16][NN];
    __shared__ int Eb[NB][16];
    __shared__ int idxs[NB];

    const int tid = threadIdx.x;
    const int bl  = (tid >= 136) ? 1 : 0;
    const int r   = tid - bl * 136;
    const int j   = r >> 2;          // 0..33 target state
    const int h   = r & 3;           // k-quarter; quads aligned (136%4==0)
    const int k0  = h * 9;
    const int bg  = blockIdx.x * NB + bl;

    // ---- init LDS score buffers (pads -1e30; init scores: START=0, else NEG)
    for (int e = tid; e < 2 * NB * NP; e += TPB) {
        int kk = e % NP;
        ((float*)sbuf)[e] = (kk >= NN) ? PADV : ((kk == 32) ? 0.0f : NEGV);
    }

    // ---- per-thread constants in registers
    float tr[9];
    int   kreg[9];
#pragma unroll
    for (int i = 0; i < 9; ++i) {
        int k = k0 + i;
        tr[i]   = (k < NN) ? trans[j * NN + k] : 0.0f;
        kreg[i] = k;
    }
    const float trE = (r < NN) ? trans[33 * NN + r] : 0.0f;

    const float* fp = feat + (size_t)bg * TT * NN + j;
    unsigned char* bpt = bpg + (size_t)bg * TT * NN + j;

    // 4-deep feature prefetch ring (t = 0..3)
    float fr0 = fp[0 * NN], fr1 = fp[1 * NN], fr2 = fp[2 * NN], fr3 = fp[3 * NN];

    float* const s0 = &sbuf[0][bl][0];
    float* const s1 = &sbuf[1][bl][0];

    __syncthreads();

    // one Viterbi step: read srd, write swr; exact fp order (s+f)+t;
    // argmax = first index attaining max (tree max + eq-scan + min-index)
    auto vstep = [&](const float* __restrict__ srd, float* __restrict__ swr,
                     float fv, unsigned char* bpw) {
        float vv[9];
#pragma unroll
        for (int i = 0; i < 9; ++i) vv[i] = (srd[k0 + i] + fv) + tr[i];
        float m = fmaxf(fmaxf(fmaxf(vv[0], vv[1]), fmaxf(vv[2], vv[3])),
                        fmaxf(fmaxf(vv[4], vv[5]), fmaxf(vv[6], vv[7])));
        m = fmaxf(m, vv[8]);
        m = fmaxf(m, dpp_f<0xB1>(m));   // quad_perm(1,0,3,2): xor 1
        m = fmaxf(m, dpp_f<0x4E>(m));   // quad_perm(2,3,0,1): xor 2
        int am = 127;
#pragma unroll
        for (int i = 8; i >= 0; --i) am = (vv[i] == m) ? kreg[i] : am;
        int ao = dpp_i<0xB1>(am); am = (ao < am) ? ao : am;
        ao = dpp_i<0x4E>(am);     am = (ao < am) ? ao : am;
        if (h == 0) { swr[j] = m; *bpw = (unsigned char)am; }
        lds_barrier();
    };

    // ---- forward: 255 iters x 4 steps (prefetch t+4) + 4-step epilogue
    for (int n = 0; n < 255; ++n) {
        { float f = fr0; fr0 = fp[4 * NN]; vstep(s0, s1, f, bpt + 0 * NN); }
        { float f = fr1; fr1 = fp[5 * NN]; vstep(s1, s0, f, bpt + 1 * NN); }
        { float f = fr2; fr2 = fp[6 * NN]; vstep(s0, s1, f, bpt + 2 * NN); }
        { float f = fr3; fr3 = fp[7 * NN]; vstep(s1, s0, f, bpt + 3 * NN); }
        fp += 4 * NN; bpt += 4 * NN;
    }
    vstep(s0, s1, fr0, bpt + 0 * NN);
    vstep(s1, s0, fr1, bpt + 1 * NN);
    vstep(s0, s1, fr2, bpt + 2 * NN);
    vstep(s1, s0, fr3, bpt + 3 * NN);
    // final scores (t=1024 even) live in sbuf[0]

    // ---- end transition + final argmax
    if (r < NN) fsb[bl][r] = s0[r] + trE;
    __syncthreads();   // also drains vmcnt: all bp stores of this wave done
    if (r == 0) {
        float bm = fsb[bl][0]; int bi = 0;
        for (int k = 1; k < NN; ++k) {
            float v = fsb[bl][k];
            if (v > bm) { bm = v; bi = k; }
        }
        out[bg] = bm; idxs[bl] = bi;
    }
    __syncthreads();

    // ---- backtrack on this block's own bp (L2-resident, same CU/XCD)
    const unsigned char* __restrict__ bb = bpg + (size_t)bg * TT * NN;

    // level-1: 16 chunks x 64 steps x 34 hypotheses; 136 thr x 4 jobs (ILP)
    {
        int g = (r >= 102) ? 3 : ((r >= 68) ? 2 : ((r >= 34) ? 1 : 0));
        int x = r - 34 * g;
        int c0 = g, c1 = g + 4, c2 = g + 8, c3 = g + 12;
        int m0 = x, m1 = x, m2 = x, m3 = x;
        for (int i = 63; i >= 0; --i) {
            m0 = bb[(size_t)((c0 * 64 + i) * NN) + m0];
            m1 = bb[(size_t)((c1 * 64 + i) * NN) + m1];
            m2 = bb[(size_t)((c2 * 64 + i) * NN) + m2];
            m3 = bb[(size_t)((c3 * 64 + i) * NN) + m3];
        }
        Fm[bl][c0][x] = m0; Fm[bl][c1][x] = m1;
        Fm[bl][c2][x] = m2; Fm[bl][c3][x] = m3;
    }
    __syncthreads();

    // level-2: serial 16-chunk scan
    if (r == 0) {
        int e = idxs[bl];
        Eb[bl][15] = e;
        for (int c = 15; c >= 1; --c) { e = Fm[bl][c][e]; Eb[bl][c - 1] = e; }
    }
    __syncthreads();

    // emit: winning hypothesis per chunk re-chases and writes the path
    float* po = out + BB + (size_t)bg * (TT + 1);
    if (r < 16) {
        int c = r;
        int m = Eb[bl][c];
        for (int i = 63; i >= 0; --i) {
            m = bb[(size_t)((c * 64 + i) * NN) + m];
            po[c * 64 + i] = (float)m;
        }
    }
    if (r == 16) po[TT] = (float)idxs[bl];
}

extern "C" void kernel_launch(void* const* d_in, const int* in_sizes, int n_in,
                              void* d_out, int out_size, void* d_ws, size_t ws_size,
                              hipStream_t stream) {
    const float* feat  = (const float*)d_in[0];   // [1024,1024,34]
    const float* trans = (const float*)d_in[1];   // [34,34]
    float* out = (float*)d_out;                   // 1024 + 1024*1025 floats
    unsigned char* bp = (unsigned char*)d_ws;     // 35,651,584 B backpointers

    viterbi_full<<<BB / NB, TPB, 0, stream>>>(feat, trans, bp, out);
}